// Round 14
// baseline (401.396 us; speedup 1.0000x reference)
//
#include <hip/hip_runtime.h>
#include <hip/hip_bf16.h>

namespace {

constexpr int T_ = 96;
constexpr int H_ = 128;

typedef short s8v __attribute__((ext_vector_type(8)));   // 8 bf16 (4 VGPR)
typedef float f4v __attribute__((ext_vector_type(4)));   // MFMA accumulator

__device__ __forceinline__ float rcp_(float x) { return __builtin_amdgcn_rcpf(x); }
__device__ __forceinline__ float sig_(float x) { return rcp_(1.f + __expf(-x)); }
__device__ __forceinline__ float tanh_(float x) { return 1.f - 2.f * rcp_(__expf(2.f * x) + 1.f); }

__device__ __forceinline__ unsigned short bf16u(float f) {
  union { float f; unsigned u; } v; v.f = f;
  unsigned r = v.u + 0x7FFFu + ((v.u >> 16) & 1u);   // RNE
  return (unsigned short)(r >> 16);
}
__device__ __forceinline__ float bf2f(unsigned short b) {
  union { unsigned u; float f; } v; v.u = ((unsigned)b) << 16;
  return v.f;
}

__device__ __forceinline__ s8v load8(const float* __restrict__ p) {
  const float4 a = *reinterpret_cast<const float4*>(p);
  const float4 b = *reinterpret_cast<const float4*>(p + 4);
  s8v r;
  r[0] = (short)bf16u(a.x); r[1] = (short)bf16u(a.y);
  r[2] = (short)bf16u(a.z); r[3] = (short)bf16u(a.w);
  r[4] = (short)bf16u(b.x); r[5] = (short)bf16u(b.y);
  r[6] = (short)bf16u(b.z); r[7] = (short)bf16u(b.w);
  return r;
}

__device__ __forceinline__ f4v mfma16(s8v a, s8v b, f4v c) {
  return __builtin_amdgcn_mfma_f32_16x16x32_bf16(a, b, c, 0, 0, 0);
}

// LDS-only barrier: do NOT drain vmcnt (hist stores stay in flight).
__device__ __forceinline__ void barrier_lds() {
  __builtin_amdgcn_sched_barrier(0);
  asm volatile("s_waitcnt lgkmcnt(0)" ::: "memory");
  __builtin_amdgcn_s_barrier();
  __builtin_amdgcn_sched_barrier(0);
}

// ---------------------------------------------------------------------------
// K0a: gate LUT (51 distinct rank-distance inputs).
// ---------------------------------------------------------------------------
__global__ __launch_bounds__(64) void k0_gate(
    const float* __restrict__ remb,
    const float* __restrict__ rw1W, const float* __restrict__ rw1b,
    const float* __restrict__ rw2W,
    float* __restrict__ glut)
{
  const int d = threadIdx.x;
  if (d > 50) return;
  const float* er = remb + d * 32;
  float g = 0.f;
#pragma unroll
  for (int e = 0; e < 16; ++e) {
    float hs = rw1b[e];
#pragma unroll 8
    for (int i = 0; i < 32; ++i) hs += er[i] * rw1W[i * 16 + e];
    g += fmaxf(hs, 0.f) * rw2W[e];
  }
  glut[d] = sig_(g);
}

// ---------------------------------------------------------------------------
// K0b: prebuild W1 MFMA B-fragments for k2.
// ---------------------------------------------------------------------------
__global__ __launch_bounds__(256) void k0_w1(
    const float* __restrict__ W1, unsigned short* __restrict__ w1f)
{
  const int e = blockIdx.x * 256 + threadIdx.x;   // 16384 elems
  const int k = e >> 7, nn = e & 127;
  const int f = ((((nn >> 4) * 4 + (k >> 5)) * 4 + ((k >> 3) & 3)) * 16 + (nn & 15)) * 8 + (k & 7);
  w1f[f] = bf16u(W1[e]);
}

// ---------------------------------------------------------------------------
// K0c: prebuild whh1 as a LINEAR B-fragment table (128KB).
// ---------------------------------------------------------------------------
__global__ __launch_bounds__(256) void k0_whh1(
    const float* __restrict__ Whh1, unsigned short* __restrict__ whh1f)
{
  const int e = blockIdx.x * 256 + threadIdx.x;   // 65536 elems (512x128)
  const int n = e >> 7, k = e & 127;
  const int g = n >> 7, wl = (n >> 4) & 7, l16 = n & 15;
  const int kt = k >> 5, lq = (k >> 3) & 3, i = k & 7;
  const int dst = (((g * 8 + wl) * 4 + kt) * 64 + lq * 16 + l16) * 8 + i;
  whh1f[dst] = bf16u(Whh1[e]);
}

// ---------------------------------------------------------------------------
// K1 (round-14): single barrier per step. Dependence audit:
//  - L0(t+1) reads h1s[cur^1] written by L0(t) before B1(t)  -> visible.
//  - L0(t+1) writes h1s[cur] (dead buffer: only L0(t) read it).
//  - L1(t) reads h1s[cur^1] + h2s[cur]; writes h2s[cur^1].
//  - dump of h2[t-1] reads h2s[cur] DURING L1 phase (both reads, safe);
//    L1(t+1) overwrites that buffer only after B1(t+1).
//  - xb[t+1] written at end of L0 phase (load issued at phase top; L0
//    compute hides the HBM latency); visible to L0(t+1) via B1(t).
// Barriers: 96+1 instead of 192; waves may drift half a step, overlapping
// L1 MFMA/LDS with other waves' L0 VALU. Register footprint unchanged.
// ---------------------------------------------------------------------------
__global__ __launch_bounds__(512) void k1_lstm_mfma(
    const float* __restrict__ x,
    const float* __restrict__ Wih0, const float* __restrict__ Whh0,
    const float* __restrict__ bih0, const float* __restrict__ bhh0,
    const float* __restrict__ Wih1, const float* __restrict__ whh1f,
    const float* __restrict__ bih1, const float* __restrict__ bhh1,
    unsigned short* __restrict__ hist)   // bf16 bits, [seq][t][unit]
{
  __shared__ __align__(16) unsigned short w1l[512 * 128];    // 128KB linear frags
  __shared__ __align__(16) unsigned short h1s[2][16 * 128];  // bf16, swizzled
  __shared__ __align__(16) unsigned short h2s[2][16 * 128];
  __shared__ __align__(16) unsigned short xb[2][16 * 32];    // A-frag layout, k>=16 zero

  const int tid  = threadIdx.x;
  const int lane = tid & 63;
  const int wv   = tid >> 6;          // wave 0..7
  const int l16  = lane & 15;
  const int lq   = lane >> 4;         // 0..3
  const int seqbase = blockIdx.x * 16;

  for (int i = tid; i < 2 * 16 * 128; i += 512) {
    (&h1s[0][0])[i] = 0; (&h2s[0][0])[i] = 0;
  }
  if (tid < 256) {  // zero the k>=16 pad of both x buffers
    const int s = tid >> 4, d = tid & 15;
    xb[0][s * 32 + 16 + d] = 0; xb[1][s * 32 + 16 + d] = 0;
    xb[0][s * 32 + d] = bf16u(x[((size_t)(seqbase + s) * T_ + 0) * 16 + d]);
  }
  {
    const uint4* src = reinterpret_cast<const uint4*>(whh1f);
    uint4* dst = reinterpret_cast<uint4*>(w1l);
    for (int i = tid; i < 8192; i += 512) dst[i] = src[i];
  }

  s8v whh0[4][4], wih1[4][4], wx0[4];
  float b0[4], b1[4];
  int wb[4];
#pragma unroll
  for (int g = 0; g < 4; ++g) {
    const int gr = g * 128 + 16 * wv + l16;   // W row = gate col
    b0[g] = bih0[gr] + bhh0[gr];
    b1[g] = bih1[gr] + bhh1[gr];
    wb[g] = ((g * 8 + wv) * 4) * 1024 + lane * 16;
#pragma unroll
    for (int kt = 0; kt < 4; ++kt) {
      const int k0 = kt * 32 + lq * 8;
      whh0[g][kt] = load8(Whh0 + (size_t)gr * 128 + k0);
      wih1[g][kt] = load8(Wih1 + (size_t)gr * 128 + k0);
    }
    if (lq < 2) wx0[g] = load8(Wih0 + (size_t)gr * 16 + lq * 8);
    else { s8v z; for (int i2 = 0; i2 < 8; ++i2) z[i2] = 0; wx0[g] = z; }
  }

  float c1[4] = {0.f, 0.f, 0.f, 0.f}, c2[4] = {0.f, 0.f, 0.f, 0.f};
  int cur = 0;
  __syncthreads();

  const int sw = (l16 & 7) << 4;
  const int hunit = 16 * wv + l16;

  for (int t = 0; t < T_; ++t) {
    const int xc = t & 1;
    // ---- issue x load for t+1 at phase top (L0 compute hides latency)
    float xv = 0.f;
    const bool xpf = (t + 1 < T_) && (tid < 256);
    if (xpf) {
      const int s = tid >> 4, d = tid & 15;
      xv = x[((size_t)(seqbase + s) * T_ + (t + 1)) * 16 + d];
    }

    // ================= L0 phase: MFMA + nonlin -> h1s[cur^1] ===============
    f4v acc[4];
#pragma unroll
    for (int g = 0; g < 4; ++g) acc[g] = f4v{b0[g], b0[g], b0[g], b0[g]};
    {
      const s8v ax = *reinterpret_cast<const s8v*>(
          reinterpret_cast<const char*>(&xb[xc][0]) + l16 * 64 + lq * 16);
#pragma unroll
      for (int g = 0; g < 4; ++g) acc[g] = mfma16(ax, wx0[g], acc[g]);
    }
#pragma unroll
    for (int kt = 0; kt < 4; ++kt) {
      const s8v ah = *reinterpret_cast<const s8v*>(
          reinterpret_cast<const char*>(&h1s[cur][0]) + l16 * 256 +
          ((kt * 64 + lq * 16) ^ sw));
#pragma unroll
      for (int g = 0; g < 4; ++g) acc[g] = mfma16(ah, whh0[g][kt], acc[g]);
    }
#pragma unroll
    for (int ss = 0; ss < 4; ++ss) {
      const int seq = lq * 4 + ss;
      const float iv = sig_(acc[0][ss]);
      const float fv = sig_(acc[1][ss]);
      const float gv = tanh_(acc[2][ss]);
      const float ov = sig_(acc[3][ss]);
      c1[ss] = fv * c1[ss] + iv * gv;
      const float hv = ov * tanh_(c1[ss]);
      *reinterpret_cast<unsigned short*>(
          reinterpret_cast<char*>(&h1s[cur ^ 1][0]) + seq * 256 +
          ((2 * hunit) ^ ((seq & 7) << 4))) = bf16u(hv);
    }
    // xb write for t+1 (visible to L0(t+1) via the barrier below)
    if (xpf) {
      const int s = tid >> 4, d = tid & 15;
      xb[xc ^ 1][s * 32 + d] = bf16u(xv);
    }
    barrier_lds();   // the ONLY barrier per step

    // ================= L1 phase: dump h2[t-1] + MFMA + nonlin ==============
    if (t >= 1) {  // dump h2[t-1] from h2s[cur] (read-only vs L1's reads)
      const int seq = tid >> 5;
      const int u0  = (tid & 31) * 4;
      const uint2 v = *reinterpret_cast<const uint2*>(
          reinterpret_cast<const char*>(&h2s[cur][0]) + seq * 256 +
          ((2 * u0) ^ ((seq & 7) << 4)));
      *reinterpret_cast<uint2*>(
          hist + ((size_t)(seqbase + seq) * T_ + (t - 1)) * H_ + u0) = v;
    }
#pragma unroll
    for (int g = 0; g < 4; ++g) acc[g] = f4v{b1[g], b1[g], b1[g], b1[g]};
#pragma unroll
    for (int kt = 0; kt < 4; ++kt) {
      const int ko = (kt * 64 + lq * 16) ^ sw;
      const s8v a1 = *reinterpret_cast<const s8v*>(
          reinterpret_cast<const char*>(&h1s[cur ^ 1][0]) + l16 * 256 + ko);
      const s8v a2 = *reinterpret_cast<const s8v*>(
          reinterpret_cast<const char*>(&h2s[cur][0]) + l16 * 256 + ko);
#pragma unroll
      for (int g = 0; g < 4; ++g) {
        acc[g] = mfma16(a1, wih1[g][kt], acc[g]);
        const s8v bw = *reinterpret_cast<const s8v*>(
            reinterpret_cast<const char*>(w1l) + wb[g] + kt * 1024);
        acc[g] = mfma16(a2, bw, acc[g]);
      }
    }
#pragma unroll
    for (int ss = 0; ss < 4; ++ss) {
      const int seq = lq * 4 + ss;
      const float iv = sig_(acc[0][ss]);
      const float fv = sig_(acc[1][ss]);
      const float gv = tanh_(acc[2][ss]);
      const float ov = sig_(acc[3][ss]);
      c2[ss] = fv * c2[ss] + iv * gv;
      const float hv = ov * tanh_(c2[ss]);
      *reinterpret_cast<unsigned short*>(
          reinterpret_cast<char*>(&h2s[cur ^ 1][0]) + seq * 256 +
          ((2 * hunit) ^ ((seq & 7) << 4))) = bf16u(hv);
    }
    cur ^= 1;   // NO second barrier
  }
  // ---- epilogue: ensure last L1 writes visible, dump h2[95] from h2s[cur]
  barrier_lds();
  {
    const int seq = tid >> 5;
    const int u0  = (tid & 31) * 4;
    const uint2 v = *reinterpret_cast<const uint2*>(
        reinterpret_cast<const char*>(&h2s[cur][0]) + seq * 256 +
        ((2 * u0) ^ ((seq & 7) << 4)));
    *reinterpret_cast<uint2*>(
        hist + ((size_t)(seqbase + seq) * T_ + (T_ - 1)) * H_ + u0) = v;
  }
}

// ---------------------------------------------------------------------------
// K2: pooling + LN1 + fused proj/qkv (round-13, verified).
// ---------------------------------------------------------------------------
__global__ __launch_bounds__(384, 2) void k2_pool_mfma(
    const unsigned short* __restrict__ hist,
    const unsigned short* __restrict__ w1f,
    const float* __restrict__ attn_w,
    const float* __restrict__ W2,
    const float* __restrict__ ln1g, const float* __restrict__ ln1b,
    const float* __restrict__ projW, const float* __restrict__ projb,
    const float* __restrict__ Wq, const float* __restrict__ bq,
    const float* __restrict__ Wk, const float* __restrict__ bk,
    const float* __restrict__ Wv, const float* __restrict__ bv,
    float* __restrict__ qb_, float* __restrict__ kb_, float* __restrict__ vb_)
{
  __shared__ __align__(16) unsigned short hst[96 * 128];
  __shared__ float sS[128], aws[128], alpha[96], wts[96], red[128], hTs[128];
  __shared__ float ctxP[3][128];
  __shared__ float xps[64];

  const int n = blockIdx.x;
  const int tid = threadIdx.x;
  const int lane = tid & 63;
  const int wv = tid >> 6;
  const int l16 = lane & 15;
  const int lq = lane >> 4;

  const unsigned short* hsrc = hist + (size_t)n * T_ * H_;
  for (int i = tid; i < 1536; i += 384) {
    const int row = i >> 4, c16 = i & 15;
    const uint4 v = *reinterpret_cast<const uint4*>(hsrc + row * 128 + c16 * 8);
    *reinterpret_cast<uint4*>(
        reinterpret_cast<char*>(hst) + row * 256 + ((c16 * 16) ^ ((row & 7) << 4))) = v;
  }
  if (tid < 128) aws[tid] = attn_w[tid];
  __syncthreads();

  if (tid < 128) hTs[tid] = bf2f(hst[95 * 128 + (tid ^ 56)]);
  __syncthreads();
  if (tid < 128) {
    float s = 0.f;
    for (int h = 0; h < 128; ++h) s += hTs[h] * W2[(size_t)h * 128 + tid];
    sS[tid] = s;
  }
  __syncthreads();

  {
    const int row0 = wv * 16 + l16;
    f4v acc[8];
#pragma unroll
    for (int nt = 0; nt < 8; ++nt) acc[nt] = f4v{0.f, 0.f, 0.f, 0.f};
#pragma unroll
    for (int kt = 0; kt < 4; ++kt) {
      const s8v a = *reinterpret_cast<const s8v*>(
          reinterpret_cast<const char*>(hst) + row0 * 256 +
          ((kt * 64 + lq * 16) ^ ((row0 & 7) << 4)));
#pragma unroll
      for (int nt = 0; nt < 8; ++nt) {
        const s8v b = *reinterpret_cast<const s8v*>(
            w1f + ((((nt << 2) + kt) << 2 | lq) * 16 + l16) * 8);
        acc[nt] = mfma16(a, b, acc[nt]);
      }
    }
    float pa[4] = {0.f, 0.f, 0.f, 0.f};
#pragma unroll
    for (int nt = 0; nt < 8; ++nt) {
      const int col = nt * 16 + l16;
      const float ss = sS[col], aw = aws[col];
#pragma unroll
      for (int i2 = 0; i2 < 4; ++i2) pa[i2] += tanh_(acc[nt][i2] + ss) * aw;
    }
#pragma unroll
    for (int i2 = 0; i2 < 4; ++i2) {
      float v = pa[i2];
      v += __shfl_xor(v, 8); v += __shfl_xor(v, 4);
      v += __shfl_xor(v, 2); v += __shfl_xor(v, 1);
      if (l16 == 0) alpha[wv * 16 + lq * 4 + i2] = v;
    }
  }
  __syncthreads();

  if (tid < 128) red[tid] = (tid < 96) ? alpha[tid] : -1e30f;
  __syncthreads();
  for (int sft = 64; sft > 0; sft >>= 1) {
    if (tid < sft) red[tid] = fmaxf(red[tid], red[tid + sft]);
    __syncthreads();
  }
  const float mx = red[0];
  __syncthreads();
  if (tid < 128) {
    const float e = (tid < 96) ? __expf(alpha[tid] - mx) : 0.f;
    red[tid] = e;
    if (tid < 96) wts[tid] = e;
  }
  __syncthreads();
  for (int sft = 64; sft > 0; sft >>= 1) {
    if (tid < sft) red[tid] += red[tid + sft];
    __syncthreads();
  }
  const float inv = rcp_(red[0]);
  if (tid < 96) wts[tid] *= inv;
  __syncthreads();

  {
    const int th = tid >> 7, j = tid & 127;
    float cp = 0.f;
    for (int t = th * 32; t < th * 32 + 32; ++t)
      cp += wts[t] * bf2f(hst[t * 128 + (j ^ ((t & 7) << 3))]);
    ctxP[th][j] = cp;
  }
  __syncthreads();
  if (tid < 128) {
    hTs[tid] = ctxP[0][tid] + ctxP[1][tid] + ctxP[2][tid];
    red[tid] = hTs[tid];
  }
  __syncthreads();
  for (int sft = 64; sft > 0; sft >>= 1) {
    if (tid < sft) red[tid] += red[tid + sft];
    __syncthreads();
  }
  const float mean = red[0] * (1.f / 128.f);
  __syncthreads();
  if (tid < 128) { const float d = hTs[tid] - mean; red[tid] = d * d; }
  __syncthreads();
  for (int sft = 64; sft > 0; sft >>= 1) {
    if (tid < sft) red[tid] += red[tid + sft];
    __syncthreads();
  }
  const float var = red[0] * (1.f / 128.f);
  __syncthreads();
  if (tid < 128)
    hTs[tid] = (hTs[tid] - mean) * rsqrtf(var + 1e-5f) * ln1g[tid] + ln1b[tid];
  __syncthreads();
  if (tid < 64) {
    float xpv = projb[tid];
    for (int kk = 0; kk < 128; ++kk) xpv += hTs[kk] * projW[kk * 64 + tid];
    xps[tid] = xpv;
  }
  __syncthreads();
  if (tid < 192) {
    const int which = tid >> 6, col = tid & 63;
    const float* W = (which == 0) ? Wq : (which == 1) ? Wk : Wv;
    const float* bb = (which == 0) ? bq : (which == 1) ? bk : bv;
    float acc = bb[col];
    for (int kk = 0; kk < 64; ++kk) acc += xps[kk] * W[kk * 64 + col];
    float* dst = (which == 0) ? qb_ : (which == 1) ? kb_ : vb_;
    dst[(size_t)n * 64 + col] = acc;
  }
}

// ---------------------------------------------------------------------------
// K4: batched attention (round-12, verified).
// ---------------------------------------------------------------------------
__global__ __launch_bounds__(512) void k4_attn_b(
    const float* __restrict__ q, const float* __restrict__ kbuf,
    const float* __restrict__ vbuf,
    const int* __restrict__ ranks, const float* __restrict__ glut,
    float* __restrict__ ao)
{
  __shared__ float Ks[128][65], Vs[128][65];
  __shared__ float qs[16][64];
  __shared__ float wrow[8][128];
  __shared__ float gl[51];
  __shared__ int rs[128];

  const int tid = threadIdx.x, lane = tid & 63, wv = tid >> 6;
  const int b = blockIdx.x >> 3;
  const int rowbase = (blockIdx.x & 7) * 16;

  for (int i = tid; i < 8192; i += 512) {
    Ks[i >> 6][i & 63] = kbuf[(size_t)b * 8192 + i];
    Vs[i >> 6][i & 63] = vbuf[(size_t)b * 8192 + i];
  }
  for (int i = tid; i < 1024; i += 512)
    qs[i >> 6][i & 63] = q[((size_t)b * 128 + rowbase) * 64 + i];
  if (tid < 128) rs[tid] = ranks[b * 128 + tid];
  if (tid >= 128 && tid < 179) gl[tid - 128] = glut[tid - 128];
  __syncthreads();

  const int m0 = lane, m1 = lane + 64;
#pragma unroll
  for (int rr = 0; rr < 2; ++rr) {
    const int lr = wv * 2 + rr;
    const int rn = rs[rowbase + lr];
    float s0 = 0.f, s1 = 0.f;
#pragma unroll 8
    for (int d = 0; d < 64; ++d) {
      const float qd = qs[lr][d];
      s0 += qd * Ks[m0][d];
      s1 += qd * Ks[m1][d];
    }
    int d0 = rn - rs[m0]; if (d0 < 0) d0 = -d0; if (d0 > 50) d0 = 50;
    int d1 = rn - rs[m1]; if (d1 < 0) d1 = -d1; if (d1 > 50) d1 = 50;
    s0 *= 0.125f * gl[d0];
    s1 *= 0.125f * gl[d1];
    float mx = fmaxf(s0, s1);
#pragma unroll
    for (int off = 32; off; off >>= 1) mx = fmaxf(mx, __shfl_xor(mx, off));
    const float e0 = __expf(s0 - mx), e1 = __expf(s1 - mx);
    float sum = e0 + e1;
#pragma unroll
    for (int off = 32; off; off >>= 1) sum += __shfl_xor(sum, off);
    const float inv = rcp_(sum);
    wrow[wv][m0] = e0 * inv;
    wrow[wv][m1] = e1 * inv;
    asm volatile("s_waitcnt lgkmcnt(0)" ::: "memory");
    float acc = 0.f;
#pragma unroll 4
    for (int m = 0; m < 128; ++m) acc += wrow[wv][m] * Vs[m][lane];
    ao[((size_t)b * 128 + rowbase + lr) * 64 + lane] = acc;
  }
}

// ---------------------------------------------------------------------------
// K5: wave-per-row FF head (round-13, verified).
// ---------------------------------------------------------------------------
__global__ __launch_bounds__(512) void k5_ffout_w(
    const float* __restrict__ ao,
    const float* __restrict__ ff1W, const float* __restrict__ ff1b,
    const float* __restrict__ ff2W, const float* __restrict__ ff2b,
    const float* __restrict__ ln2g, const float* __restrict__ ln2b,
    const float* __restrict__ sp1W, const float* __restrict__ sp1b,
    const float* __restrict__ sp2W, const float* __restrict__ sp2b,
    float* __restrict__ out)
{
  __shared__ float f1[64][128];    // ff1W, 32KB
  __shared__ float f2[128][64];    // ff2W, 32KB
  __shared__ float s1[64][32];     // sp1W, 8KB
  __shared__ float f1b[128], f2b[64], g2[64], b2[64], s1b[32], s2w[32];
  __shared__ float hbuf[8][128], fbuf[8][64];

  const int tid = threadIdx.x, lane = tid & 63, wv = tid >> 6;
  for (int i = tid; i < 8192; i += 512) f1[i >> 7][i & 127] = ff1W[i];
  for (int i = tid; i < 8192; i += 512) f2[i >> 6][i & 63] = ff2W[i];
  for (int i = tid; i < 2048; i += 512) s1[i >> 5][i & 31] = sp1W[i];
  if (tid < 128) f1b[tid] = ff1b[tid];
  else if (tid < 192) f2b[tid - 128] = ff2b[tid - 128];
  else if (tid < 256) g2[tid - 192] = ln2g[tid - 192];
  else if (tid < 320) b2[tid - 256] = ln2b[tid - 256];
  else if (tid < 352) s1b[tid - 320] = sp1b[tid - 320];
  else if (tid < 384) s2w[tid - 352] = sp2W[tid - 352];
  __syncthreads();

  const int row = blockIdx.x * 8 + wv;
  const float a = ao[(size_t)row * 64 + lane];
  float h0 = f1b[lane], h1 = f1b[lane + 64];
#pragma unroll 8
  for (int d = 0; d < 64; ++d) {
    const float ad = __shfl(a, d);
    h0 += ad * f1[d][lane];
    h1 += ad * f1[d][lane + 64];
  }
  hbuf[wv][lane] = fmaxf(h0, 0.f);
  hbuf[wv][lane + 64] = fmaxf(h1, 0.f);
  __syncthreads();

  float yv = f2b[lane];
#pragma unroll 8
  for (int j = 0; j < 128; ++j) yv += hbuf[wv][j] * f2[j][lane];
  float s = yv;
#pragma unroll
  for (int off = 32; off; off >>= 1) s += __shfl_xor(s, off);
  const float mean = s * (1.f / 64.f);
  float d2 = (yv - mean) * (yv - mean);
#pragma unroll
  for (int off = 32; off; off >>= 1) d2 += __shfl_xor(d2, off);
  const float var = d2 * (1.f / 64.f);
  fbuf[wv][lane] = (yv - mean) * rsqrtf(var + 1e-5f) * g2[lane] + b2[lane];
  __syncthreads();

  float val = 0.f;
  if (lane < 32) {
    float h2v = s1b[lane];
#pragma unroll 8
    for (int c = 0; c < 64; ++c) h2v += fbuf[wv][c] * s1[c][lane];
    val = fmaxf(h2v, 0.f) * s2w[lane];
  }
#pragma unroll
  for (int off = 16; off; off >>= 1) val += __shfl_xor(val, off);
  if (lane == 0) out[row] = sig_(val + sp2b[0]);
}

}  // namespace

extern "C" void kernel_launch(void* const* d_in, const int* in_sizes, int n_in,
                              void* d_out, int out_size, void* d_ws, size_t ws_size,
                              hipStream_t stream)
{
  const float* x      = (const float*)d_in[0];
  const int*   ranks  = (const int*)  d_in[1];
  const float* Wih0   = (const float*)d_in[2];
  const float* Whh0   = (const float*)d_in[3];
  const float* bih0   = (const float*)d_in[4];
  const float* bhh0   = (const float*)d_in[5];
  const float* Wih1   = (const float*)d_in[6];
  const float* Whh1   = (const float*)d_in[7];
  const float* bih1   = (const float*)d_in[8];
  const float* bhh1   = (const float*)d_in[9];
  const float* attn_w = (const float*)d_in[10];
  const float* W1     = (const float*)d_in[11];
  const float* W2     = (const float*)d_in[12];
  const float* ln1g   = (const float*)d_in[13];
  const float* ln1b   = (const float*)d_in[14];
  const float* projW  = (const float*)d_in[15];
  const float* projb  = (const float*)d_in[16];
  const float* Wq     = (const float*)d_in[17];
  const float* bq     = (const float*)d_in[18];
  const float* Wk     = (const float*)d_in[19];
  const float* bk     = (const float*)d_in[20];
  const float* Wv     = (const float*)d_in[21];
  const float* bv     = (const float*)d_in[22];
  const float* remb   = (const float*)d_in[23];
  const float* rw1W   = (const float*)d_in[24];
  const float* rw1b   = (const float*)d_in[25];
  const float* rw2W   = (const float*)d_in[26];
  const float* ff1W   = (const float*)d_in[27];
  const float* ff1b   = (const float*)d_in[28];
  const float* ff2W   = (const float*)d_in[29];
  const float* ff2b   = (const float*)d_in[30];
  const float* ln2g   = (const float*)d_in[31];
  const float* ln2b   = (const float*)d_in[32];
  const float* sp1W   = (const float*)d_in[33];
  const float* sp1b   = (const float*)d_in[34];
  const float* sp2W   = (const float*)d_in[35];
  const float* sp2b   = (const float*)d_in[36];
  float* out = (float*)d_out;

  char* ws = (char*)d_ws;
  unsigned short* hist = (unsigned short*)ws;            // 4096*96*128 bf16 = 96 MB
  size_t off = (size_t)4096 * 96 * 128 * 2;
  float* rep = (float*)(ws + off); off += (size_t)4096 * 128 * 4;  // unused (kept layout)
  float* qb  = (float*)(ws + off); off += (size_t)4096 * 64 * 4;
  float* kb  = (float*)(ws + off); off += (size_t)4096 * 64 * 4;
  float* vb  = (float*)(ws + off); off += (size_t)4096 * 64 * 4;
  float* aob = (float*)(ws + off); off += (size_t)4096 * 64 * 4;
  unsigned short* w1f   = (unsigned short*)(ws + off); off += 16384 * 2;
  float* glut = (float*)(ws + off); off += 64 * 4;
  unsigned short* whh1f = (unsigned short*)(ws + off); off += 65536 * 2;
  (void)rep;

  k0_gate<<<dim3(1), dim3(64), 0, stream>>>(remb, rw1W, rw1b, rw2W, glut);
  k0_w1<<<dim3(64), dim3(256), 0, stream>>>(W1, w1f);
  k0_whh1<<<dim3(256), dim3(256), 0, stream>>>(Whh1, whh1f);
  k1_lstm_mfma<<<dim3(256), dim3(512), 0, stream>>>(
      x, Wih0, Whh0, bih0, bhh0, Wih1, (const float*)whh1f, bih1, bhh1, hist);
  k2_pool_mfma<<<dim3(4096), dim3(384), 0, stream>>>(
      hist, w1f, attn_w, W2, ln1g, ln1b,
      projW, projb, Wq, bq, Wk, bk, Wv, bv, qb, kb, vb);
  k4_attn_b<<<dim3(256), dim3(512), 0, stream>>>(
      qb, kb, vb, ranks, glut, aob);
  k5_ffout_w<<<dim3(512), dim3(512), 0, stream>>>(
      aob, ff1W, ff1b, ff2W, ff2b, ln2g, ln2b, sp1W, sp1b, sp2W, sp2b, out);
}

// Round 15
// 394.120 us; speedup vs baseline: 1.0185x; 1.0185x over previous
//
#include <hip/hip_runtime.h>
#include <hip/hip_bf16.h>

namespace {

constexpr int T_ = 96;
constexpr int H_ = 128;

typedef short s8v __attribute__((ext_vector_type(8)));   // 8 bf16 (4 VGPR)
typedef float f4v __attribute__((ext_vector_type(4)));   // MFMA accumulator

__device__ __forceinline__ float rcp_(float x) { return __builtin_amdgcn_rcpf(x); }
__device__ __forceinline__ float sig_(float x) { return rcp_(1.f + __expf(-x)); }
__device__ __forceinline__ float tanh_(float x) { return 1.f - 2.f * rcp_(__expf(2.f * x) + 1.f); }

__device__ __forceinline__ unsigned short bf16u(float f) {
  union { float f; unsigned u; } v; v.f = f;
  unsigned r = v.u + 0x7FFFu + ((v.u >> 16) & 1u);   // RNE
  return (unsigned short)(r >> 16);
}
__device__ __forceinline__ float bf2f(unsigned short b) {
  union { unsigned u; float f; } v; v.u = ((unsigned)b) << 16;
  return v.f;
}

__device__ __forceinline__ s8v load8(const float* __restrict__ p) {
  const float4 a = *reinterpret_cast<const float4*>(p);
  const float4 b = *reinterpret_cast<const float4*>(p + 4);
  s8v r;
  r[0] = (short)bf16u(a.x); r[1] = (short)bf16u(a.y);
  r[2] = (short)bf16u(a.z); r[3] = (short)bf16u(a.w);
  r[4] = (short)bf16u(b.x); r[5] = (short)bf16u(b.y);
  r[6] = (short)bf16u(b.z); r[7] = (short)bf16u(b.w);
  return r;
}

__device__ __forceinline__ f4v mfma16(s8v a, s8v b, f4v c) {
  return __builtin_amdgcn_mfma_f32_16x16x32_bf16(a, b, c, 0, 0, 0);
}

// LDS-only barrier: do NOT drain vmcnt (hist stores stay in flight).
__device__ __forceinline__ void barrier_lds() {
  __builtin_amdgcn_sched_barrier(0);
  asm volatile("s_waitcnt lgkmcnt(0)" ::: "memory");
  __builtin_amdgcn_s_barrier();
  __builtin_amdgcn_sched_barrier(0);
}

// ---------------------------------------------------------------------------
// K0a: gate LUT (51 distinct rank-distance inputs).
// ---------------------------------------------------------------------------
__global__ __launch_bounds__(64) void k0_gate(
    const float* __restrict__ remb,
    const float* __restrict__ rw1W, const float* __restrict__ rw1b,
    const float* __restrict__ rw2W,
    float* __restrict__ glut)
{
  const int d = threadIdx.x;
  if (d > 50) return;
  const float* er = remb + d * 32;
  float g = 0.f;
#pragma unroll
  for (int e = 0; e < 16; ++e) {
    float hs = rw1b[e];
#pragma unroll 8
    for (int i = 0; i < 32; ++i) hs += er[i] * rw1W[i * 16 + e];
    g += fmaxf(hs, 0.f) * rw2W[e];
  }
  glut[d] = sig_(g);
}

// ---------------------------------------------------------------------------
// K0b: prebuild W1 MFMA B-fragments for k2.
// ---------------------------------------------------------------------------
__global__ __launch_bounds__(256) void k0_w1(
    const float* __restrict__ W1, unsigned short* __restrict__ w1f)
{
  const int e = blockIdx.x * 256 + threadIdx.x;   // 16384 elems
  const int k = e >> 7, nn = e & 127;
  const int f = ((((nn >> 4) * 4 + (k >> 5)) * 4 + ((k >> 3) & 3)) * 16 + (nn & 15)) * 8 + (k & 7);
  w1f[f] = bf16u(W1[e]);
}

// ---------------------------------------------------------------------------
// K0c: prebuild whh1 as a LINEAR B-fragment table (128KB).
// ---------------------------------------------------------------------------
__global__ __launch_bounds__(256) void k0_whh1(
    const float* __restrict__ Whh1, unsigned short* __restrict__ whh1f)
{
  const int e = blockIdx.x * 256 + threadIdx.x;   // 65536 elems (512x128)
  const int n = e >> 7, k = e & 127;
  const int g = n >> 7, wl = (n >> 4) & 7, l16 = n & 15;
  const int kt = k >> 5, lq = (k >> 3) & 3, i = k & 7;
  const int dst = (((g * 8 + wl) * 4 + kt) * 64 + lq * 16 + l16) * 8 + i;
  whh1f[dst] = bf16u(Whh1[e]);
}

// ---------------------------------------------------------------------------
// K1: two-layer LSTM via MFMA — EXACT round-10/12/13 kernel (282us floor).
// r14's single-barrier variant regressed (300us, +reg pressure): the
// 2-barrier lockstep phase structure is what lets the compiler keep the
// register footprint at 128 with no spill. FROZEN.
// ---------------------------------------------------------------------------
__global__ __launch_bounds__(512) void k1_lstm_mfma(
    const float* __restrict__ x,
    const float* __restrict__ Wih0, const float* __restrict__ Whh0,
    const float* __restrict__ bih0, const float* __restrict__ bhh0,
    const float* __restrict__ Wih1, const float* __restrict__ whh1f,
    const float* __restrict__ bih1, const float* __restrict__ bhh1,
    unsigned short* __restrict__ hist)   // bf16 bits, [seq][t][unit]
{
  __shared__ __align__(16) unsigned short w1l[512 * 128];    // 128KB linear frags
  __shared__ __align__(16) unsigned short h1s[2][16 * 128];  // bf16, swizzled
  __shared__ __align__(16) unsigned short h2s[2][16 * 128];
  __shared__ __align__(16) unsigned short xb[2][16 * 32];    // A-frag layout, k>=16 zero

  const int tid  = threadIdx.x;
  const int lane = tid & 63;
  const int wv   = tid >> 6;          // wave 0..7
  const int l16  = lane & 15;
  const int lq   = lane >> 4;         // 0..3
  const int seqbase = blockIdx.x * 16;

  for (int i = tid; i < 2 * 16 * 128; i += 512) {
    (&h1s[0][0])[i] = 0; (&h2s[0][0])[i] = 0;
  }
  if (tid < 256) {  // zero the k>=16 pad of both x buffers
    const int s = tid >> 4, d = tid & 15;
    xb[0][s * 32 + 16 + d] = 0; xb[1][s * 32 + 16 + d] = 0;
    xb[0][s * 32 + d] = bf16u(x[((size_t)(seqbase + s) * T_ + 0) * 16 + d]);
  }
  {
    const uint4* src = reinterpret_cast<const uint4*>(whh1f);
    uint4* dst = reinterpret_cast<uint4*>(w1l);
    for (int i = tid; i < 8192; i += 512) dst[i] = src[i];
  }

  s8v whh0[4][4], wih1[4][4], wx0[4];
  float b0[4], b1[4];
  int wb[4];
#pragma unroll
  for (int g = 0; g < 4; ++g) {
    const int gr = g * 128 + 16 * wv + l16;   // W row = gate col
    b0[g] = bih0[gr] + bhh0[gr];
    b1[g] = bih1[gr] + bhh1[gr];
    wb[g] = ((g * 8 + wv) * 4) * 1024 + lane * 16;
#pragma unroll
    for (int kt = 0; kt < 4; ++kt) {
      const int k0 = kt * 32 + lq * 8;
      whh0[g][kt] = load8(Whh0 + (size_t)gr * 128 + k0);
      wih1[g][kt] = load8(Wih1 + (size_t)gr * 128 + k0);
    }
    if (lq < 2) wx0[g] = load8(Wih0 + (size_t)gr * 16 + lq * 8);
    else { s8v z; for (int i2 = 0; i2 < 8; ++i2) z[i2] = 0; wx0[g] = z; }
  }

  float c1[4] = {0.f, 0.f, 0.f, 0.f}, c2[4] = {0.f, 0.f, 0.f, 0.f};
  int cur = 0;
  __syncthreads();

  const int sw = (l16 & 7) << 4;
  const int hunit = 16 * wv + l16;

  for (int t = 0; t < T_; ++t) {
    const int xc = t & 1;
    float xv = 0.f;
    const bool xpf = (t + 1 < T_) && (tid < 256);
    if (xpf) {
      const int s = tid >> 4, d = tid & 15;
      xv = x[((size_t)(seqbase + s) * T_ + (t + 1)) * 16 + d];
    }

    // ================= layer-0 MFMA =================
    f4v acc[4];
#pragma unroll
    for (int g = 0; g < 4; ++g) acc[g] = f4v{b0[g], b0[g], b0[g], b0[g]};
    {
      const s8v ax = *reinterpret_cast<const s8v*>(
          reinterpret_cast<const char*>(&xb[xc][0]) + l16 * 64 + lq * 16);
#pragma unroll
      for (int g = 0; g < 4; ++g) acc[g] = mfma16(ax, wx0[g], acc[g]);
    }
#pragma unroll
    for (int kt = 0; kt < 4; ++kt) {
      const s8v ah = *reinterpret_cast<const s8v*>(
          reinterpret_cast<const char*>(&h1s[cur][0]) + l16 * 256 +
          ((kt * 64 + lq * 16) ^ sw));
#pragma unroll
      for (int g = 0; g < 4; ++g) acc[g] = mfma16(ah, whh0[g][kt], acc[g]);
    }
#pragma unroll
    for (int ss = 0; ss < 4; ++ss) {
      const int seq = lq * 4 + ss;
      const float iv = sig_(acc[0][ss]);
      const float fv = sig_(acc[1][ss]);
      const float gv = tanh_(acc[2][ss]);
      const float ov = sig_(acc[3][ss]);
      c1[ss] = fv * c1[ss] + iv * gv;
      const float hv = ov * tanh_(c1[ss]);
      *reinterpret_cast<unsigned short*>(
          reinterpret_cast<char*>(&h1s[cur ^ 1][0]) + seq * 256 +
          ((2 * hunit) ^ ((seq & 7) << 4))) = bf16u(hv);
    }
    barrier_lds();

    // ================= layer-1 MFMA =================
#pragma unroll
    for (int g = 0; g < 4; ++g) acc[g] = f4v{b1[g], b1[g], b1[g], b1[g]};
#pragma unroll
    for (int kt = 0; kt < 4; ++kt) {
      const int ko = (kt * 64 + lq * 16) ^ sw;
      const s8v a1 = *reinterpret_cast<const s8v*>(
          reinterpret_cast<const char*>(&h1s[cur ^ 1][0]) + l16 * 256 + ko);
      const s8v a2 = *reinterpret_cast<const s8v*>(
          reinterpret_cast<const char*>(&h2s[cur][0]) + l16 * 256 + ko);
#pragma unroll
      for (int g = 0; g < 4; ++g) {
        acc[g] = mfma16(a1, wih1[g][kt], acc[g]);
        const s8v bw = *reinterpret_cast<const s8v*>(
            reinterpret_cast<const char*>(w1l) + wb[g] + kt * 1024);
        acc[g] = mfma16(a2, bw, acc[g]);
      }
    }
#pragma unroll
    for (int ss = 0; ss < 4; ++ss) {
      const int seq = lq * 4 + ss;
      const float iv = sig_(acc[0][ss]);
      const float fv = sig_(acc[1][ss]);
      const float gv = tanh_(acc[2][ss]);
      const float ov = sig_(acc[3][ss]);
      c2[ss] = fv * c2[ss] + iv * gv;
      const float hv = ov * tanh_(c2[ss]);
      *reinterpret_cast<unsigned short*>(
          reinterpret_cast<char*>(&h2s[cur ^ 1][0]) + seq * 256 +
          ((2 * hunit) ^ ((seq & 7) << 4))) = bf16u(hv);
    }
    if (xpf) {
      const int s = tid >> 4, d = tid & 15;
      xb[xc ^ 1][s * 32 + d] = bf16u(xv);
    }
    barrier_lds();

    {
      const int seq = tid >> 5;
      const int u0  = (tid & 31) * 4;
      const uint2 v = *reinterpret_cast<const uint2*>(
          reinterpret_cast<const char*>(&h2s[cur ^ 1][0]) + seq * 256 +
          ((2 * u0) ^ ((seq & 7) << 4)));
      *reinterpret_cast<uint2*>(
          hist + ((size_t)(seqbase + seq) * T_ + t) * H_ + u0) = v;
    }
    cur ^= 1;
  }
}

// ---------------------------------------------------------------------------
// K2: pooling + LN1 + fused proj/qkv (round-13, verified).
// ---------------------------------------------------------------------------
__global__ __launch_bounds__(384, 2) void k2_pool_mfma(
    const unsigned short* __restrict__ hist,
    const unsigned short* __restrict__ w1f,
    const float* __restrict__ attn_w,
    const float* __restrict__ W2,
    const float* __restrict__ ln1g, const float* __restrict__ ln1b,
    const float* __restrict__ projW, const float* __restrict__ projb,
    const float* __restrict__ Wq, const float* __restrict__ bq,
    const float* __restrict__ Wk, const float* __restrict__ bk,
    const float* __restrict__ Wv, const float* __restrict__ bv,
    float* __restrict__ qb_, float* __restrict__ kb_, float* __restrict__ vb_)
{
  __shared__ __align__(16) unsigned short hst[96 * 128];
  __shared__ float sS[128], aws[128], alpha[96], wts[96], red[128], hTs[128];
  __shared__ float ctxP[3][128];
  __shared__ float xps[64];

  const int n = blockIdx.x;
  const int tid = threadIdx.x;
  const int lane = tid & 63;
  const int wv = tid >> 6;
  const int l16 = lane & 15;
  const int lq = lane >> 4;

  const unsigned short* hsrc = hist + (size_t)n * T_ * H_;
  for (int i = tid; i < 1536; i += 384) {
    const int row = i >> 4, c16 = i & 15;
    const uint4 v = *reinterpret_cast<const uint4*>(hsrc + row * 128 + c16 * 8);
    *reinterpret_cast<uint4*>(
        reinterpret_cast<char*>(hst) + row * 256 + ((c16 * 16) ^ ((row & 7) << 4))) = v;
  }
  if (tid < 128) aws[tid] = attn_w[tid];
  __syncthreads();

  if (tid < 128) hTs[tid] = bf2f(hst[95 * 128 + (tid ^ 56)]);
  __syncthreads();
  if (tid < 128) {
    float s = 0.f;
    for (int h = 0; h < 128; ++h) s += hTs[h] * W2[(size_t)h * 128 + tid];
    sS[tid] = s;
  }
  __syncthreads();

  {
    const int row0 = wv * 16 + l16;
    f4v acc[8];
#pragma unroll
    for (int nt = 0; nt < 8; ++nt) acc[nt] = f4v{0.f, 0.f, 0.f, 0.f};
#pragma unroll
    for (int kt = 0; kt < 4; ++kt) {
      const s8v a = *reinterpret_cast<const s8v*>(
          reinterpret_cast<const char*>(hst) + row0 * 256 +
          ((kt * 64 + lq * 16) ^ ((row0 & 7) << 4)));
#pragma unroll
      for (int nt = 0; nt < 8; ++nt) {
        const s8v b = *reinterpret_cast<const s8v*>(
            w1f + ((((nt << 2) + kt) << 2 | lq) * 16 + l16) * 8);
        acc[nt] = mfma16(a, b, acc[nt]);
      }
    }
    float pa[4] = {0.f, 0.f, 0.f, 0.f};
#pragma unroll
    for (int nt = 0; nt < 8; ++nt) {
      const int col = nt * 16 + l16;
      const float ss = sS[col], aw = aws[col];
#pragma unroll
      for (int i2 = 0; i2 < 4; ++i2) pa[i2] += tanh_(acc[nt][i2] + ss) * aw;
    }
#pragma unroll
    for (int i2 = 0; i2 < 4; ++i2) {
      float v = pa[i2];
      v += __shfl_xor(v, 8); v += __shfl_xor(v, 4);
      v += __shfl_xor(v, 2); v += __shfl_xor(v, 1);
      if (l16 == 0) alpha[wv * 16 + lq * 4 + i2] = v;
    }
  }
  __syncthreads();

  if (tid < 128) red[tid] = (tid < 96) ? alpha[tid] : -1e30f;
  __syncthreads();
  for (int sft = 64; sft > 0; sft >>= 1) {
    if (tid < sft) red[tid] = fmaxf(red[tid], red[tid + sft]);
    __syncthreads();
  }
  const float mx = red[0];
  __syncthreads();
  if (tid < 128) {
    const float e = (tid < 96) ? __expf(alpha[tid] - mx) : 0.f;
    red[tid] = e;
    if (tid < 96) wts[tid] = e;
  }
  __syncthreads();
  for (int sft = 64; sft > 0; sft >>= 1) {
    if (tid < sft) red[tid] += red[tid + sft];
    __syncthreads();
  }
  const float inv = rcp_(red[0]);
  if (tid < 96) wts[tid] *= inv;
  __syncthreads();

  {
    const int th = tid >> 7, j = tid & 127;
    float cp = 0.f;
    for (int t = th * 32; t < th * 32 + 32; ++t)
      cp += wts[t] * bf2f(hst[t * 128 + (j ^ ((t & 7) << 3))]);
    ctxP[th][j] = cp;
  }
  __syncthreads();
  if (tid < 128) {
    hTs[tid] = ctxP[0][tid] + ctxP[1][tid] + ctxP[2][tid];
    red[tid] = hTs[tid];
  }
  __syncthreads();
  for (int sft = 64; sft > 0; sft >>= 1) {
    if (tid < sft) red[tid] += red[tid + sft];
    __syncthreads();
  }
  const float mean = red[0] * (1.f / 128.f);
  __syncthreads();
  if (tid < 128) { const float d = hTs[tid] - mean; red[tid] = d * d; }
  __syncthreads();
  for (int sft = 64; sft > 0; sft >>= 1) {
    if (tid < sft) red[tid] += red[tid + sft];
    __syncthreads();
  }
  const float var = red[0] * (1.f / 128.f);
  __syncthreads();
  if (tid < 128)
    hTs[tid] = (hTs[tid] - mean) * rsqrtf(var + 1e-5f) * ln1g[tid] + ln1b[tid];
  __syncthreads();
  if (tid < 64) {
    float xpv = projb[tid];
    for (int kk = 0; kk < 128; ++kk) xpv += hTs[kk] * projW[kk * 64 + tid];
    xps[tid] = xpv;
  }
  __syncthreads();
  if (tid < 192) {
    const int which = tid >> 6, col = tid & 63;
    const float* W = (which == 0) ? Wq : (which == 1) ? Wk : Wv;
    const float* bb = (which == 0) ? bq : (which == 1) ? bk : bv;
    float acc = bb[col];
    for (int kk = 0; kk < 64; ++kk) acc += xps[kk] * W[kk * 64 + col];
    float* dst = (which == 0) ? qb_ : (which == 1) ? kb_ : vb_;
    dst[(size_t)n * 64 + col] = acc;
  }
}

// ---------------------------------------------------------------------------
// K4: batched attention (round-12, verified).
// ---------------------------------------------------------------------------
__global__ __launch_bounds__(512) void k4_attn_b(
    const float* __restrict__ q, const float* __restrict__ kbuf,
    const float* __restrict__ vbuf,
    const int* __restrict__ ranks, const float* __restrict__ glut,
    float* __restrict__ ao)
{
  __shared__ float Ks[128][65], Vs[128][65];
  __shared__ float qs[16][64];
  __shared__ float wrow[8][128];
  __shared__ float gl[51];
  __shared__ int rs[128];

  const int tid = threadIdx.x, lane = tid & 63, wv = tid >> 6;
  const int b = blockIdx.x >> 3;
  const int rowbase = (blockIdx.x & 7) * 16;

  for (int i = tid; i < 8192; i += 512) {
    Ks[i >> 6][i & 63] = kbuf[(size_t)b * 8192 + i];
    Vs[i >> 6][i & 63] = vbuf[(size_t)b * 8192 + i];
  }
  for (int i = tid; i < 1024; i += 512)
    qs[i >> 6][i & 63] = q[((size_t)b * 128 + rowbase) * 64 + i];
  if (tid < 128) rs[tid] = ranks[b * 128 + tid];
  if (tid >= 128 && tid < 179) gl[tid - 128] = glut[tid - 128];
  __syncthreads();

  const int m0 = lane, m1 = lane + 64;
#pragma unroll
  for (int rr = 0; rr < 2; ++rr) {
    const int lr = wv * 2 + rr;
    const int rn = rs[rowbase + lr];
    float s0 = 0.f, s1 = 0.f;
#pragma unroll 8
    for (int d = 0; d < 64; ++d) {
      const float qd = qs[lr][d];
      s0 += qd * Ks[m0][d];
      s1 += qd * Ks[m1][d];
    }
    int d0 = rn - rs[m0]; if (d0 < 0) d0 = -d0; if (d0 > 50) d0 = 50;
    int d1 = rn - rs[m1]; if (d1 < 0) d1 = -d1; if (d1 > 50) d1 = 50;
    s0 *= 0.125f * gl[d0];
    s1 *= 0.125f * gl[d1];
    float mx = fmaxf(s0, s1);
#pragma unroll
    for (int off = 32; off; off >>= 1) mx = fmaxf(mx, __shfl_xor(mx, off));
    const float e0 = __expf(s0 - mx), e1 = __expf(s1 - mx);
    float sum = e0 + e1;
#pragma unroll
    for (int off = 32; off; off >>= 1) sum += __shfl_xor(sum, off);
    const float inv = rcp_(sum);
    wrow[wv][m0] = e0 * inv;
    wrow[wv][m1] = e1 * inv;
    asm volatile("s_waitcnt lgkmcnt(0)" ::: "memory");
    float acc = 0.f;
#pragma unroll 4
    for (int m = 0; m < 128; ++m) acc += wrow[wv][m] * Vs[m][lane];
    ao[((size_t)b * 128 + rowbase + lr) * 64 + lane] = acc;
  }
}

// ---------------------------------------------------------------------------
// K5: wave-per-row FF head (round-13, verified).
// ---------------------------------------------------------------------------
__global__ __launch_bounds__(512) void k5_ffout_w(
    const float* __restrict__ ao,
    const float* __restrict__ ff1W, const float* __restrict__ ff1b,
    const float* __restrict__ ff2W, const float* __restrict__ ff2b,
    const float* __restrict__ ln2g, const float* __restrict__ ln2b,
    const float* __restrict__ sp1W, const float* __restrict__ sp1b,
    const float* __restrict__ sp2W, const float* __restrict__ sp2b,
    float* __restrict__ out)
{
  __shared__ float f1[64][128];    // ff1W, 32KB
  __shared__ float f2[128][64];    // ff2W, 32KB
  __shared__ float s1[64][32];     // sp1W, 8KB
  __shared__ float f1b[128], f2b[64], g2[64], b2[64], s1b[32], s2w[32];
  __shared__ float hbuf[8][128], fbuf[8][64];

  const int tid = threadIdx.x, lane = tid & 63, wv = tid >> 6;
  for (int i = tid; i < 8192; i += 512) f1[i >> 7][i & 127] = ff1W[i];
  for (int i = tid; i < 8192; i += 512) f2[i >> 6][i & 63] = ff2W[i];
  for (int i = tid; i < 2048; i += 512) s1[i >> 5][i & 31] = sp1W[i];
  if (tid < 128) f1b[tid] = ff1b[tid];
  else if (tid < 192) f2b[tid - 128] = ff2b[tid - 128];
  else if (tid < 256) g2[tid - 192] = ln2g[tid - 192];
  else if (tid < 320) b2[tid - 256] = ln2b[tid - 256];
  else if (tid < 352) s1b[tid - 320] = sp1b[tid - 320];
  else if (tid < 384) s2w[tid - 352] = sp2W[tid - 352];
  __syncthreads();

  const int row = blockIdx.x * 8 + wv;
  const float a = ao[(size_t)row * 64 + lane];
  float h0 = f1b[lane], h1 = f1b[lane + 64];
#pragma unroll 8
  for (int d = 0; d < 64; ++d) {
    const float ad = __shfl(a, d);
    h0 += ad * f1[d][lane];
    h1 += ad * f1[d][lane + 64];
  }
  hbuf[wv][lane] = fmaxf(h0, 0.f);
  hbuf[wv][lane + 64] = fmaxf(h1, 0.f);
  __syncthreads();

  float yv = f2b[lane];
#pragma unroll 8
  for (int j = 0; j < 128; ++j) yv += hbuf[wv][j] * f2[j][lane];
  float s = yv;
#pragma unroll
  for (int off = 32; off; off >>= 1) s += __shfl_xor(s, off);
  const float mean = s * (1.f / 64.f);
  float d2 = (yv - mean) * (yv - mean);
#pragma unroll
  for (int off = 32; off; off >>= 1) d2 += __shfl_xor(d2, off);
  const float var = d2 * (1.f / 64.f);
  fbuf[wv][lane] = (yv - mean) * rsqrtf(var + 1e-5f) * g2[lane] + b2[lane];
  __syncthreads();

  float val = 0.f;
  if (lane < 32) {
    float h2v = s1b[lane];
#pragma unroll 8
    for (int c = 0; c < 64; ++c) h2v += fbuf[wv][c] * s1[c][lane];
    val = fmaxf(h2v, 0.f) * s2w[lane];
  }
#pragma unroll
  for (int off = 16; off; off >>= 1) val += __shfl_xor(val, off);
  if (lane == 0) out[row] = sig_(val + sp2b[0]);
}

}  // namespace

extern "C" void kernel_launch(void* const* d_in, const int* in_sizes, int n_in,
                              void* d_out, int out_size, void* d_ws, size_t ws_size,
                              hipStream_t stream)
{
  const float* x      = (const float*)d_in[0];
  const int*   ranks  = (const int*)  d_in[1];
  const float* Wih0   = (const float*)d_in[2];
  const float* Whh0   = (const float*)d_in[3];
  const float* bih0   = (const float*)d_in[4];
  const float* bhh0   = (const float*)d_in[5];
  const float* Wih1   = (const float*)d_in[6];
  const float* Whh1   = (const float*)d_in[7];
  const float* bih1   = (const float*)d_in[8];
  const float* bhh1   = (const float*)d_in[9];
  const float* attn_w = (const float*)d_in[10];
  const float* W1     = (const float*)d_in[11];
  const float* W2     = (const float*)d_in[12];
  const float* ln1g   = (const float*)d_in[13];
  const float* ln1b   = (const float*)d_in[14];
  const float* projW  = (const float*)d_in[15];
  const float* projb  = (const float*)d_in[16];
  const float* Wq     = (const float*)d_in[17];
  const float* bq     = (const float*)d_in[18];
  const float* Wk     = (const float*)d_in[19];
  const float* bk     = (const float*)d_in[20];
  const float* Wv     = (const float*)d_in[21];
  const float* bv     = (const float*)d_in[22];
  const float* remb   = (const float*)d_in[23];
  const float* rw1W   = (const float*)d_in[24];
  const float* rw1b   = (const float*)d_in[25];
  const float* rw2W   = (const float*)d_in[26];
  const float* ff1W   = (const float*)d_in[27];
  const float* ff1b   = (const float*)d_in[28];
  const float* ff2W   = (const float*)d_in[29];
  const float* ff2b   = (const float*)d_in[30];
  const float* ln2g   = (const float*)d_in[31];
  const float* ln2b   = (const float*)d_in[32];
  const float* sp1W   = (const float*)d_in[33];
  const float* sp1b   = (const float*)d_in[34];
  const float* sp2W   = (const float*)d_in[35];
  const float* sp2b   = (const float*)d_in[36];
  float* out = (float*)d_out;

  char* ws = (char*)d_ws;
  unsigned short* hist = (unsigned short*)ws;            // 4096*96*128 bf16 = 96 MB
  size_t off = (size_t)4096 * 96 * 128 * 2;
  float* rep = (float*)(ws + off); off += (size_t)4096 * 128 * 4;  // unused (kept layout)
  float* qb  = (float*)(ws + off); off += (size_t)4096 * 64 * 4;
  float* kb  = (float*)(ws + off); off += (size_t)4096 * 64 * 4;
  float* vb  = (float*)(ws + off); off += (size_t)4096 * 64 * 4;
  float* aob = (float*)(ws + off); off += (size_t)4096 * 64 * 4;
  unsigned short* w1f   = (unsigned short*)(ws + off); off += 16384 * 2;
  float* glut = (float*)(ws + off); off += 64 * 4;
  unsigned short* whh1f = (unsigned short*)(ws + off); off += 65536 * 2;
  (void)rep;

  k0_gate<<<dim3(1), dim3(64), 0, stream>>>(remb, rw1W, rw1b, rw2W, glut);
  k0_w1<<<dim3(64), dim3(256), 0, stream>>>(W1, w1f);
  k0_whh1<<<dim3(256), dim3(256), 0, stream>>>(Whh1, whh1f);
  k1_lstm_mfma<<<dim3(256), dim3(512), 0, stream>>>(
      x, Wih0, Whh0, bih0, bhh0, Wih1, (const float*)whh1f, bih1, bhh1, hist);
  k2_pool_mfma<<<dim3(4096), dim3(384), 0, stream>>>(
      hist, w1f, attn_w, W2, ln1g, ln1b,
      projW, projb, Wq, bq, Wk, bk, Wv, bv, qb, kb, vb);
  k4_attn_b<<<dim3(256), dim3(512), 0, stream>>>(
      qb, kb, vb, ranks, glut, aob);
  k5_ffout_w<<<dim3(512), dim3(512), 0, stream>>>(
      aob, ff1W, ff1b, ff2W, ff2b, ln2g, ln2b, sp1W, sp1b, sp2W, sp2b, out);
}